// Round 8
// baseline (156.853 us; speedup 1.0000x reference)
//
#include <hip/hip_runtime.h>
#include <cstdint>
#include <cstddef>

#define WDIM 1600
#define BDIM 4
#define HDIM 900
#define NV4  225   // float4s per column (900/4)
#define QCAP 96    // max valid radar entries per column (mean ~27, sigma ~5.1)
#define KBIG (4 * HDIM)
#define BW   6     // query batch width
#define NWAVE 2    // waves (columns) per block: 3200 blocks -> 12.5 blocks/CU

// wave64 f32 min via DPP (row_shr 1/2/4/8, row_bcast15/31); result in lane 63.
#define DPP_MINF(v, ctrl)                                                  \
    v = fminf(v, __int_as_float(__builtin_amdgcn_update_dpp(               \
            __float_as_int(v), __float_as_int(v), ctrl, 0xf, 0xf, false)))
// wave64 i32 min via DPP; result in lane 63.
#define DPP_MINI(v, ctrl)                                                  \
    { int _t = __builtin_amdgcn_update_dpp(v, v, ctrl, 0xf, 0xf, false);   \
      v = _t < v ? _t : v; }

__device__ __forceinline__ float rdlane_f(float v, int l) {
    return __int_as_float(__builtin_amdgcn_readlane(__float_as_int(v), l));
}

// Phase 1: one wave per (w,b) column, 2 columns per block, no barriers
// (per-wave private LDS regions; DS ops within a wave are ordered).
__global__ __launch_bounds__(64 * NWAVE, 8) void radar_place_kernel(
    const float* __restrict__ radar, const float* __restrict__ mde,
    float* __restrict__ colout /* (W*B, H) */, int direct, float* __restrict__ out)
{
    __shared__ __align__(16) float s_col[NWAVE][HDIM];
    __shared__ float s_qd[NWAVE][QCAP];
    __shared__ int   s_qy[NWAVE][QCAP];

    const int wave = threadIdx.x >> 6;
    const int lane = threadIdx.x & 63;
    const int colid = blockIdx.x * NWAVE + wave;   // grid exactly W*B/NWAVE
    const float4* mde4   = (const float4*)mde   + (long)colid * NV4;
    const float4* radar4 = (const float4*)radar + (long)colid * NV4;

    float*  colw = s_col[wave];
    float4* col4 = (float4*)colw;
    float*  qd   = s_qd[wave];
    int*    qy   = s_qy[wave];

    const unsigned long long below = (1ull << lane) - 1ull;

    // --- A1: coalesced mde load -> stash raw into colw (scratch) ---
    bool hm = false;
#pragma unroll
    for (int c = 0; c < 4; ++c) {
        int i4 = c * 64 + lane;
        if (i4 < NV4) {
            float4 mv = mde4[i4];
            hm = hm || (mv.x != 0.f) || (mv.y != 0.f) || (mv.z != 0.f) || (mv.w != 0.f);
            col4[i4] = mv;
        }
    }
    const bool has_mde = (__ballot(hm) != 0ull);

    // --- A2: radar load + ascending-y compaction into qd/qy ---
    int Q = 0;
#pragma unroll
    for (int c = 0; c < 4; ++c) {
        int i4 = c * 64 + lane;
        bool in = (i4 < NV4);
        float4 rv = in ? radar4[i4] : make_float4(0.f, 0.f, 0.f, 0.f);
        unsigned long long b0 = __ballot(rv.x != 0.f);
        unsigned long long b1 = __ballot(rv.y != 0.f);
        unsigned long long b2 = __ballot(rv.z != 0.f);
        unsigned long long b3 = __ballot(rv.w != 0.f);
        int pos = Q + __popcll(b0 & below) + __popcll(b1 & below)
                    + __popcll(b2 & below) + __popcll(b3 & below);
        int y0 = i4 * 4;
        if (rv.x != 0.f) { if (pos < QCAP) { qd[pos] = rv.x; qy[pos] = y0;     } pos++; }
        if (rv.y != 0.f) { if (pos < QCAP) { qd[pos] = rv.y; qy[pos] = y0 + 1; } pos++; }
        if (rv.z != 0.f) { if (pos < QCAP) { qd[pos] = rv.z; qy[pos] = y0 + 2; } pos++; }
        if (rv.w != 0.f) { if (pos < QCAP) { qd[pos] = rv.w; qy[pos] = y0 + 3; } pos++; }
        Q += __popcll(b0) + __popcll(b1) + __popcll(b2) + __popcll(b3);
    }
    if (Q > QCAP) Q = QCAP;

    // --- A3: redistribute mde lane-major: lane l owns y = l*15+k (900 = 60*15) ---
    float m[15];
    if (lane < 60) {
        int yb = lane * 15;
#pragma unroll
        for (int k = 0; k < 15; ++k) {
            float v = colw[yb + k];        // stride 15 (odd) => conflict-free
            m[k] = (v != 0.f) ? v : 1e30f;
        }
    } else {
#pragma unroll
        for (int k = 0; k < 15; ++k) m[k] = 1e30f;
    }

    // --- A4: pull query list into register banks (lane q <-> query q) ---
    float dq_lo = 0.f, dq_hi = 0.f;
    int   qy_lo = 0,   qy_hi = 0;
    if (lane < Q)      { dq_lo = qd[lane];      qy_lo = qy[lane]; }
    if (lane + 64 < Q) { dq_hi = qd[lane + 64]; qy_hi = qy[lane + 64]; }

    // --- A5: zero output column (after A3 reads; in-wave DS order is safe) ---
#pragma unroll
    for (int c = 0; c < 4; ++c) {
        int i4 = c * 64 + lane;
        if (i4 < NV4) col4[i4] = make_float4(0.f, 0.f, 0.f, 0.f);
    }

    // --- Stage B: argmin prepass; results deposited into best_lo/hi ---
    int best_lo = 0, best_hi = 0;
    for (int t = 0; t < Q; t += BW) {
        int idxs[BW];       // uniform
        float d[BW];        // uniform broadcast into the scan
#pragma unroll
        for (int i = 0; i < BW; ++i) {
            int idx = t + i; if (idx >= Q) idx = Q - 1;
            idxs[i] = idx;
            if (idx < 64) d[i] = rdlane_f(dq_lo, idx);
            else          d[i] = rdlane_f(dq_hi, idx - 64);
        }
        float bd[BW], bo[BW];
        int bik[BW];
#pragma unroll
        for (int i = 0; i < BW; ++i) { bd[i] = 3.4e38f; bik[i] = 0; }
        // per-lane scan over 15 contiguous y: k ascending => first index kept
#pragma unroll
        for (int k = 0; k < 15; ++k) {
            float mm = m[k];
#pragma unroll
            for (int i = 0; i < BW; ++i) {
                float af = fabsf(mm - d[i]);
                if (af < bd[i]) { bd[i] = af; bik[i] = k; }
            }
        }
#pragma unroll
        for (int i = 0; i < BW; ++i) bo[i] = bd[i];
#pragma unroll
        for (int i = 0; i < BW; ++i) DPP_MINF(bd[i], 0x111);
#pragma unroll
        for (int i = 0; i < BW; ++i) DPP_MINF(bd[i], 0x112);
#pragma unroll
        for (int i = 0; i < BW; ++i) DPP_MINF(bd[i], 0x114);
#pragma unroll
        for (int i = 0; i < BW; ++i) DPP_MINF(bd[i], 0x118);
#pragma unroll
        for (int i = 0; i < BW; ++i) DPP_MINF(bd[i], 0x142);
#pragma unroll
        for (int i = 0; i < BW; ++i) DPP_MINF(bd[i], 0x143);
#pragma unroll
        for (int i = 0; i < BW; ++i) {
            int idx = idxs[i];
            int sb;
            if (has_mde) {
                float gm = rdlane_f(bd[i], 63);
                // first lane holding the min; lane-major layout => lowest lane
                // = lowest y block; its first-k => global first index (exact).
                unsigned long long wm = __ballot(bo[i] == gm);
                int win = __ffsll((long long)wm) - 1;
                int kst = __builtin_amdgcn_readlane(bik[i], win);
                sb = win * 15 + kst;
            } else {
                if (idx < 64) sb = __builtin_amdgcn_readlane(qy_lo, idx);
                else          sb = __builtin_amdgcn_readlane(qy_hi, idx - 64);
            }
            // deposit: idx is wave-uniform => exec-masked move (writelane-equiv)
            if (idx < 64) { if (lane == idx)      best_lo = sb; }
            else          { if (lane == idx - 64) best_hi = sb; }
        }
    }

    // occupancy: bit k of lane l <=> y = l*15+k occupied; lanes >= 60 inert
    unsigned occ = (lane >= 60) ? 0x7FFFu : 0u;
    int fy_lo = 0, fy_hi = 0;

    // --- Stage C: sequential placement, pure SALU/VALU (no LDS, no shfl) ---
    auto place_one = [&](int sb) -> int {
        int bl = sb / 15, bk = sb - bl * 15;     // uniform scalars
        unsigned long long bm = __ballot((occ >> bk) & 1u);
        int fy = sb;
        if ((bm >> bl) & 1ull) {
            // slow path (rare): key = occ ? KBIG : 2|dy|+(dy<0); argmin.
            // key injective below KBIG => unique winner lane.
            int ko = 0x7fffffff, kk = 0;
#pragma unroll
            for (int k = 0; k < 15; ++k) {
                int yy = lane * 15 + k;
                int o = (occ >> k) & 1;
                int dy = yy - sb;
                int ad = dy < 0 ? -dy : dy;
                int key = o ? KBIG : (2 * ad + (dy < 0 ? 1 : 0));
                if (key < ko) { ko = key; kk = k; }
            }
            int km = ko;
            DPP_MINI(km, 0x111); DPP_MINI(km, 0x112); DPP_MINI(km, 0x114);
            DPP_MINI(km, 0x118); DPP_MINI(km, 0x142); DPP_MINI(km, 0x143);
            int gkm = __builtin_amdgcn_readlane(km, 63);
            if (gkm < KBIG) {
                unsigned long long wm2 = __ballot(ko == gkm);
                int w2 = __ffsll((long long)wm2) - 1;
                int k2 = __builtin_amdgcn_readlane(kk, w2);
                fy = w2 * 15 + k2;
            }
        }
        int fl2 = fy / 15, fk2 = fy - (fy / 15) * 15;
        if (lane == fl2) occ |= (1u << fk2);
        return fy;
    };

    int Qlo = Q < 64 ? Q : 64;
    for (int q = 0; q < Qlo; ++q) {
        int fy = place_one(__builtin_amdgcn_readlane(best_lo, q));
        if (lane == q) fy_lo = fy;       // q uniform => exec-masked move
    }
    for (int q = 64; q < Q; ++q) {
        int fy = place_one(__builtin_amdgcn_readlane(best_hi, q - 64));
        if (lane == q - 64) fy_hi = fy;
    }

    // --- Stage D: one scattered DS write per bank (final slots are unique) ---
    if (lane < Q)      colw[fy_lo] = dq_lo;
    if (lane + 64 < Q) colw[fy_hi] = dq_hi;

    // --- writeout ---
    if (direct) {
        int w_ = colid >> 2, b_ = colid & 3;
#pragma unroll
        for (int c = 0; c < 4; ++c) {
            int i4 = c * 64 + lane;
            if (i4 < NV4) {
                float4 v = col4[i4];
                int y = i4 * 4;
                out[((long)(b_ * HDIM + y + 0)) * WDIM + w_] = v.x;
                out[((long)(b_ * HDIM + y + 1)) * WDIM + w_] = v.y;
                out[((long)(b_ * HDIM + y + 2)) * WDIM + w_] = v.z;
                out[((long)(b_ * HDIM + y + 3)) * WDIM + w_] = v.w;
            }
        }
    } else {
        float4* colout4 = (float4*)colout + (long)colid * NV4;
#pragma unroll
        for (int c = 0; c < 4; ++c) {
            int i4 = c * 64 + lane;
            if (i4 < NV4) colout4[i4] = col4[i4];
        }
    }
}

// Phase 2: transpose (W*B, H) -> (B, H, W), fully coalesced both sides.
__global__ __launch_bounds__(256) void transpose_kernel(
    const float* __restrict__ colout, float* __restrict__ out)
{
    __shared__ float tile[32][33];
    const int b  = blockIdx.z;
    const int h0 = blockIdx.x * 32;
    const int w0 = blockIdx.y * 32;
    const int tx = threadIdx.x & 31;
    const int ty = threadIdx.x >> 5;  // 0..7
#pragma unroll
    for (int j = 0; j < 4; ++j) {
        int wl = ty + j * 8;
        int w = w0 + wl;
        int h = h0 + tx;
        float v = 0.0f;
        if (h < HDIM && w < WDIM) v = colout[((long)(w * BDIM + b)) * HDIM + h];
        tile[wl][tx] = v;
    }
    __syncthreads();
#pragma unroll
    for (int j = 0; j < 4; ++j) {
        int hl = ty + j * 8;
        int h = h0 + hl;
        int w = w0 + tx;
        if (h < HDIM && w < WDIM)
            out[((long)(b * HDIM + h)) * WDIM + w] = tile[tx][hl];
    }
}

extern "C" void kernel_launch(void* const* d_in, const int* in_sizes, int n_in,
                              void* d_out, int out_size, void* d_ws, size_t ws_size,
                              hipStream_t stream) {
    const float* radar = (const float*)d_in[0];
    const float* mde   = (const float*)d_in[1];
    float* out = (float*)d_out;
    float* ws  = (float*)d_ws;

    const size_t need = (size_t)WDIM * BDIM * HDIM * sizeof(float);
    const int direct = (ws_size < need) ? 1 : 0;

    hipLaunchKernelGGL(radar_place_kernel,
                       dim3(WDIM * BDIM / NWAVE), dim3(64 * NWAVE), 0, stream,
                       radar, mde, ws, direct, out);

    if (!direct) {
        dim3 g((HDIM + 31) / 32, WDIM / 32, BDIM);
        hipLaunchKernelGGL(transpose_kernel, g, dim3(256), 0, stream, ws, out);
    }
}

// Round 9
// 137.457 us; speedup vs baseline: 1.1411x; 1.1411x over previous
//
#include <hip/hip_runtime.h>
#include <cstdint>
#include <cstddef>

#define WDIM 1600
#define BDIM 4
#define HDIM 900
#define NV4  225   // float4s per column (900/4)
#define QCAP 96    // max valid radar entries per column (mean ~27, sigma ~5.1)
#define KBIG (4 * HDIM)
#define BW   9     // query batch width (Q~27 -> 3 batches)
#define NWAVE 4    // waves (columns) per block

// wave64 f32 min via DPP (row_shr 1/2/4/8, row_bcast15/31); result in lane 63.
#define DPP_MINF(v, ctrl)                                                  \
    v = fminf(v, __int_as_float(__builtin_amdgcn_update_dpp(               \
            __float_as_int(v), __float_as_int(v), ctrl, 0xf, 0xf, false)))
// wave64 i32 min via DPP; result in lane 63.
#define DPP_MINI(v, ctrl)                                                  \
    { int _t = __builtin_amdgcn_update_dpp(v, v, ctrl, 0xf, 0xf, false);   \
      v = _t < v ? _t : v; }

__device__ __forceinline__ float rdlane_f(float v, int l) {
    return __int_as_float(__builtin_amdgcn_readlane(__float_as_int(v), l));
}

// pack (lane, k, y) for stage-C shift-decode: y<=899 (10b), k<16 (4b), lane<60 (6b)
__device__ __forceinline__ int pack_lky(int l, int k) {
    return (l << 20) | (k << 16) | (l * 15 + k);
}

// Phase 1: one wave per (w,b) column, 4 columns per block, no barriers
// (per-wave private LDS regions; DS ops within a wave are ordered).
__global__ __launch_bounds__(64 * NWAVE, 7) void radar_place_kernel(
    const float* __restrict__ radar, const float* __restrict__ mde,
    float* __restrict__ colout /* (W*B, H) */, int direct, float* __restrict__ out)
{
    __shared__ __align__(16) float s_col[NWAVE][HDIM];
    __shared__ float s_qd[NWAVE][QCAP];
    __shared__ int   s_qy[NWAVE][QCAP];

    const int wave = threadIdx.x >> 6;
    const int lane = threadIdx.x & 63;
    const int colid = blockIdx.x * NWAVE + wave;   // grid exactly W*B/NWAVE
    const float4* mde4   = (const float4*)mde   + (long)colid * NV4;
    const float4* radar4 = (const float4*)radar + (long)colid * NV4;

    float*  colw = s_col[wave];
    float4* col4 = (float4*)colw;
    float*  qd   = s_qd[wave];
    int*    qy   = s_qy[wave];

    const unsigned long long below = (1ull << lane) - 1ull;

    // --- A1: coalesced mde load -> stash raw into colw (scratch) ---
    bool hm = false;
#pragma unroll
    for (int c = 0; c < 4; ++c) {
        int i4 = c * 64 + lane;
        if (i4 < NV4) {
            float4 mv = mde4[i4];
            hm = hm || (mv.x != 0.f) || (mv.y != 0.f) || (mv.z != 0.f) || (mv.w != 0.f);
            col4[i4] = mv;
        }
    }
    const bool has_mde = (__ballot(hm) != 0ull);

    // --- A2: radar load + ascending-y compaction into qd/qy ---
    int Q = 0;
#pragma unroll
    for (int c = 0; c < 4; ++c) {
        int i4 = c * 64 + lane;
        bool in = (i4 < NV4);
        float4 rv = in ? radar4[i4] : make_float4(0.f, 0.f, 0.f, 0.f);
        unsigned long long b0 = __ballot(rv.x != 0.f);
        unsigned long long b1 = __ballot(rv.y != 0.f);
        unsigned long long b2 = __ballot(rv.z != 0.f);
        unsigned long long b3 = __ballot(rv.w != 0.f);
        int pos = Q + __popcll(b0 & below) + __popcll(b1 & below)
                    + __popcll(b2 & below) + __popcll(b3 & below);
        int y0 = i4 * 4;
        if (rv.x != 0.f) { if (pos < QCAP) { qd[pos] = rv.x; qy[pos] = y0;     } pos++; }
        if (rv.y != 0.f) { if (pos < QCAP) { qd[pos] = rv.y; qy[pos] = y0 + 1; } pos++; }
        if (rv.z != 0.f) { if (pos < QCAP) { qd[pos] = rv.z; qy[pos] = y0 + 2; } pos++; }
        if (rv.w != 0.f) { if (pos < QCAP) { qd[pos] = rv.w; qy[pos] = y0 + 3; } pos++; }
        Q += __popcll(b0) + __popcll(b1) + __popcll(b2) + __popcll(b3);
    }
    if (Q > QCAP) Q = QCAP;

    // --- A3: redistribute mde lane-major: lane l owns y = l*15+k (900 = 60*15) ---
    float m[15];
    if (lane < 60) {
        int yb = lane * 15;
#pragma unroll
        for (int k = 0; k < 15; ++k) {
            float v = colw[yb + k];        // stride 15 (odd) => conflict-free
            m[k] = (v != 0.f) ? v : 1e30f;
        }
    } else {
#pragma unroll
        for (int k = 0; k < 15; ++k) m[k] = 1e30f;
    }

    // --- A4: pull query list into register banks (lane q <-> query q) ---
    float dq_lo = 0.f, dq_hi = 0.f;
    if (lane < Q)      dq_lo = qd[lane];
    if (lane + 64 < Q) dq_hi = qd[lane + 64];

    // --- A5: zero output column (after A3 reads; in-wave DS order is safe) ---
#pragma unroll
    for (int c = 0; c < 4; ++c) {
        int i4 = c * 64 + lane;
        if (i4 < NV4) col4[i4] = make_float4(0.f, 0.f, 0.f, 0.f);
    }

    // --- Stage B: argmin prepass; packed (lane,k,y) deposited into best_lo/hi ---
    int best_lo = 0, best_hi = 0;
    const int Qlo = Q < 64 ? Q : 64;

    if (has_mde) {
        for (int t = 0; t < Qlo; t += BW) {
            float d[BW];
#pragma unroll
            for (int i = 0; i < BW; ++i) {
                int idx = t + i; if (idx >= Qlo) idx = Qlo - 1;
                d[i] = rdlane_f(dq_lo, idx);   // uniform SGPR broadcast
            }
            float bd[BW], bo[BW];
            int bik[BW];
#pragma unroll
            for (int i = 0; i < BW; ++i) { bd[i] = 3.4e38f; bik[i] = 0; }
            // per-lane scan over 15 contiguous y: k ascending => first index kept
#pragma unroll
            for (int k = 0; k < 15; ++k) {
                float mm = m[k];
#pragma unroll
                for (int i = 0; i < BW; ++i) {
                    float af = fabsf(mm - d[i]);
                    if (af < bd[i]) { bd[i] = af; bik[i] = k; }
                }
            }
#pragma unroll
            for (int i = 0; i < BW; ++i) bo[i] = bd[i];
#pragma unroll
            for (int i = 0; i < BW; ++i) DPP_MINF(bd[i], 0x111);
#pragma unroll
            for (int i = 0; i < BW; ++i) DPP_MINF(bd[i], 0x112);
#pragma unroll
            for (int i = 0; i < BW; ++i) DPP_MINF(bd[i], 0x114);
#pragma unroll
            for (int i = 0; i < BW; ++i) DPP_MINF(bd[i], 0x118);
#pragma unroll
            for (int i = 0; i < BW; ++i) DPP_MINF(bd[i], 0x142);
#pragma unroll
            for (int i = 0; i < BW; ++i) DPP_MINF(bd[i], 0x143);
#pragma unroll
            for (int i = 0; i < BW; ++i) {
                int idx = t + i;
                if (idx < Qlo) {
                    float gm = rdlane_f(bd[i], 63);
                    // first lane holding the min; lane-major layout => lowest lane
                    // = lowest y block; its first-k => global first index (exact).
                    unsigned long long wm = __ballot(bo[i] == gm);
                    int win = __ffsll((long long)wm) - 1;
                    int kst = __builtin_amdgcn_readlane(bik[i], win);
                    int pk = pack_lky(win, kst);
                    if (lane == idx) best_lo = pk;   // uniform idx => masked move
                }
            }
        }
        if (Q > 64) {   // cold: Q>64 ~never happens for 3% density
            for (int t = 64; t < Q; t += 1) {
                float d0 = rdlane_f(dq_hi, t - 64);
                float bd0 = 3.4e38f, bo0; int bik0 = 0;
#pragma unroll
                for (int k = 0; k < 15; ++k) {
                    float af = fabsf(m[k] - d0);
                    if (af < bd0) { bd0 = af; bik0 = k; }
                }
                bo0 = bd0;
                DPP_MINF(bd0, 0x111); DPP_MINF(bd0, 0x112); DPP_MINF(bd0, 0x114);
                DPP_MINF(bd0, 0x118); DPP_MINF(bd0, 0x142); DPP_MINF(bd0, 0x143);
                float gm = rdlane_f(bd0, 63);
                unsigned long long wm = __ballot(bo0 == gm);
                int win = __ffsll((long long)wm) - 1;
                int kst = __builtin_amdgcn_readlane(bik0, win);
                int pk = pack_lky(win, kst);
                if (lane == t - 64) best_hi = pk;
            }
        }
    } else {            // cold: no valid mde; best = query's own y
        for (int q = 0; q < Q; ++q) {
            int y = qy[q];
            int l = y / 15, k = y - l * 15;
            int pk = pack_lky(l, k);
            if (q < 64) { if (lane == q)      best_lo = pk; }
            else        { if (lane == q - 64) best_hi = pk; }
        }
    }

    // occupancy: bit k of lane l <=> y = l*15+k occupied; lanes >= 60 inert
    unsigned occ = (lane >= 60) ? 0x7FFFu : 0u;
    int fy_lo = 0, fy_hi = 0;

    // --- Stage C: sequential placement; probe via dynamic readlane, no div ---
    auto place_one = [&](int pk) -> int {
        int bl = pk >> 20, bk = (pk >> 16) & 15;          // uniform scalars
        unsigned po = (unsigned)__builtin_amdgcn_readlane((int)occ, bl);
        int fpk = pk;
        if ((po >> bk) & 1u) {
            // slow path (rare): key = occ ? KBIG : 2|dy|+(dy<0); argmin.
            // key injective below KBIG => unique winner lane.
            int sy = pk & 0xffff;
            int ko = 0x7fffffff, kk = 0;
#pragma unroll
            for (int k = 0; k < 15; ++k) {
                int yy = lane * 15 + k;
                int o = (occ >> k) & 1;
                int dy = yy - sy;
                int ad = dy < 0 ? -dy : dy;
                int key = o ? KBIG : (2 * ad + (dy < 0 ? 1 : 0));
                if (key < ko) { ko = key; kk = k; }
            }
            int km = ko;
            DPP_MINI(km, 0x111); DPP_MINI(km, 0x112); DPP_MINI(km, 0x114);
            DPP_MINI(km, 0x118); DPP_MINI(km, 0x142); DPP_MINI(km, 0x143);
            int gkm = __builtin_amdgcn_readlane(km, 63);
            if (gkm < KBIG) {
                unsigned long long wm2 = __ballot(ko == gkm);
                int w2 = __ffsll((long long)wm2) - 1;
                int k2 = __builtin_amdgcn_readlane(kk, w2);
                fpk = pack_lky(w2, k2);
            }
        }
        int fl = fpk >> 20, fk = (fpk >> 16) & 15;
        if (lane == fl) occ |= (1u << fk);
        return fpk;
    };

    for (int q = 0; q < Qlo; ++q) {
        int fpk = place_one(__builtin_amdgcn_readlane(best_lo, q));
        if (lane == q) fy_lo = fpk;      // q uniform => exec-masked move
    }
    if (Q > 64) {
        for (int q = 64; q < Q; ++q) {
            int fpk = place_one(__builtin_amdgcn_readlane(best_hi, q - 64));
            if (lane == q - 64) fy_hi = fpk;
        }
    }

    // --- Stage D: one scattered DS write per bank (final slots are unique) ---
    if (lane < Q)      colw[fy_lo & 0xffff] = dq_lo;
    if (lane + 64 < Q) colw[fy_hi & 0xffff] = dq_hi;

    // --- writeout ---
    if (direct) {
        int w_ = colid >> 2, b_ = colid & 3;
#pragma unroll
        for (int c = 0; c < 4; ++c) {
            int i4 = c * 64 + lane;
            if (i4 < NV4) {
                float4 v = col4[i4];
                int y = i4 * 4;
                out[((long)(b_ * HDIM + y + 0)) * WDIM + w_] = v.x;
                out[((long)(b_ * HDIM + y + 1)) * WDIM + w_] = v.y;
                out[((long)(b_ * HDIM + y + 2)) * WDIM + w_] = v.z;
                out[((long)(b_ * HDIM + y + 3)) * WDIM + w_] = v.w;
            }
        }
    } else {
        float4* colout4 = (float4*)colout + (long)colid * NV4;
#pragma unroll
        for (int c = 0; c < 4; ++c) {
            int i4 = c * 64 + lane;
            if (i4 < NV4) colout4[i4] = col4[i4];
        }
    }
}

// Phase 2: transpose (W*B, H) -> (B, H, W), fully coalesced both sides.
__global__ __launch_bounds__(256) void transpose_kernel(
    const float* __restrict__ colout, float* __restrict__ out)
{
    __shared__ float tile[32][33];
    const int b  = blockIdx.z;
    const int h0 = blockIdx.x * 32;
    const int w0 = blockIdx.y * 32;
    const int tx = threadIdx.x & 31;
    const int ty = threadIdx.x >> 5;  // 0..7
#pragma unroll
    for (int j = 0; j < 4; ++j) {
        int wl = ty + j * 8;
        int w = w0 + wl;
        int h = h0 + tx;
        float v = 0.0f;
        if (h < HDIM && w < WDIM) v = colout[((long)(w * BDIM + b)) * HDIM + h];
        tile[wl][tx] = v;
    }
    __syncthreads();
#pragma unroll
    for (int j = 0; j < 4; ++j) {
        int hl = ty + j * 8;
        int h = h0 + hl;
        int w = w0 + tx;
        if (h < HDIM && w < WDIM)
            out[((long)(b * HDIM + h)) * WDIM + w] = tile[tx][hl];
    }
}

extern "C" void kernel_launch(void* const* d_in, const int* in_sizes, int n_in,
                              void* d_out, int out_size, void* d_ws, size_t ws_size,
                              hipStream_t stream) {
    const float* radar = (const float*)d_in[0];
    const float* mde   = (const float*)d_in[1];
    float* out = (float*)d_out;
    float* ws  = (float*)d_ws;

    const size_t need = (size_t)WDIM * BDIM * HDIM * sizeof(float);
    const int direct = (ws_size < need) ? 1 : 0;

    hipLaunchKernelGGL(radar_place_kernel,
                       dim3(WDIM * BDIM / NWAVE), dim3(64 * NWAVE), 0, stream,
                       radar, mde, ws, direct, out);

    if (!direct) {
        dim3 g((HDIM + 31) / 32, WDIM / 32, BDIM);
        hipLaunchKernelGGL(transpose_kernel, g, dim3(256), 0, stream, ws, out);
    }
}